// Round 1
// 169.717 us; speedup vs baseline: 1.0330x; 1.0330x over previous
//
#include <hip/hip_runtime.h>
#include <hip/hip_bf16.h>
#include <math.h>

#define NN 256
#define CC 128
#define HH 4
#define DD 32

typedef uint4 u128;
typedef __bf16 bf16x8 __attribute__((ext_vector_type(8)));
typedef float f32x4 __attribute__((ext_vector_type(4)));

#define LOG2E 1.4426950408889634f
#define QSC (0.17677669529663687f * LOG2E)   // 1/sqrt(32) * log2(e), folded into q

// ---------------------------------------------------------------------------
// K0 prep: biasM[j][k] = (mask[j][k] ? -inf : dscale*dm[j][k]) * log2e
//          Wt_qkv[n][k] = bf16(Wqkv[k][n]); Wt_out[n][k] = bf16(Wout[k][n])
//          Abf = bf16(pair_rep)   (so K1 stages bf16 directly, no per-block cvt)
// ---------------------------------------------------------------------------
__global__ __launch_bounds__(256) void prep_kernel(
    const float* __restrict__ dm, const int* __restrict__ mask,
    const float* __restrict__ dscale,
    const float* __restrict__ Wqkv, const float* __restrict__ Wout,
    const float* __restrict__ pair,
    float* __restrict__ biasM,
    __hip_bfloat16* __restrict__ Wt_qkv, __hip_bfloat16* __restrict__ Wt_out,
    __hip_bfloat16* __restrict__ Abf)
{
    const int b = blockIdx.x, t = threadIdx.x;
    if (b < 256) {
        int idx = b * 256 + t;                 // coalesced both sides
        biasM[idx] = mask[idx] ? -INFINITY : dscale[0] * dm[idx] * LOG2E;
    } else if (b < 448) {
        int idx = (b - 256) * 256 + t;         // [0, 49152)
        int n = idx >> 7, k = idx & 127;
        Wt_qkv[idx] = __float2bfloat16(Wqkv[(size_t)k * 384 + n]);
    } else if (b < 512) {
        int idx = (b - 448) * 256 + t;         // [0, 16384)
        int n = idx >> 7, k = idx & 127;
        Wt_out[idx] = __float2bfloat16(Wout[(size_t)k * CC + n]);
    } else {
        // pair_rep fp32 -> bf16, 8 elems/thread, 4096 blocks
        size_t e = (size_t)(b - 512) * 2048 + (size_t)t * 8;
        float4 v0 = *(const float4*)(pair + e);
        float4 v1 = *(const float4*)(pair + e + 4);
        __hip_bfloat162 a01 = __float22bfloat162_rn(float2{v0.x, v0.y});
        __hip_bfloat162 a23 = __float22bfloat162_rn(float2{v0.z, v0.w});
        __hip_bfloat162 a45 = __float22bfloat162_rn(float2{v1.x, v1.y});
        __hip_bfloat162 a67 = __float22bfloat162_rn(float2{v1.z, v1.w});
        u128 pk;
        pk.x = *(unsigned int*)&a01;
        pk.y = *(unsigned int*)&a23;
        pk.z = *(unsigned int*)&a45;
        pk.w = *(unsigned int*)&a67;
        *(u128*)&Abf[e] = pk;
    }
}

// ---------------------------------------------------------------------------
// K1: qkv = pair_rep @ Wqkv + bqkv  (MFMA, operand-swapped: C[n][m])
// A arrives pre-converted bf16 -> staging is 4x u128 copies (half the bytes,
// no VALU convert). 512 threads (8 waves); per-wave 2mt x 3nt x 4k = 24 MFMAs.
// q columns (n<128) pre-scaled by QSC for the attention exp2 path.
// ---------------------------------------------------------------------------
__global__ __launch_bounds__(512, 4) void qkv_mfma_kernel(
    const __hip_bfloat16* __restrict__ A,     // [65536,128] bf16
    const __hip_bfloat16* __restrict__ Bt,    // [384,128] bf16 (transposed W)
    const float* __restrict__ bias,           // [384]
    __hip_bfloat16* __restrict__ out)         // [65536,384]
{
    __shared__ __align__(16) __hip_bfloat16 As[128][136];
    __shared__ __align__(16) __hip_bfloat16 Bs[96][136];
    const int t = threadIdx.x;
    const int m0 = blockIdx.x * 128;
    const int n0 = blockIdx.y * 96;

    #pragma unroll
    for (int it = 0; it < 4; ++it) {           // A: bf16 u128 copies
        int idx = it * 512 + t;
        int r = idx >> 4, c8 = (idx & 15) * 8;
        *(u128*)&As[r][c8] = *(const u128*)(A + (size_t)(m0 + r) * CC + c8);
    }
    #pragma unroll
    for (int it = 0; it < 3; ++it) {
        int idx = it * 512 + t;
        int n = idx >> 4, c8 = (idx & 15) * 8;
        *(u128*)&Bs[n][c8] = *(const u128*)(Bt + (size_t)(n0 + n) * CC + c8);
    }
    __syncthreads();

    const int w = t >> 6, lane = t & 63;
    const int n16 = lane & 15, quad = lane >> 4;
    const int mw = (w & 3) * 32, nw = (w >> 2) * 48;

    bf16x8 pf[2][4];                           // B-operand: pair rows [m][k]
    #pragma unroll
    for (int mt = 0; mt < 2; ++mt)
        #pragma unroll
        for (int ks = 0; ks < 4; ++ks)
            pf[mt][ks] = *(const bf16x8*)&As[mw + mt * 16 + n16][ks * 32 + quad * 8];

    f32x4 acc[2][3];
    #pragma unroll
    for (int mt = 0; mt < 2; ++mt)
        #pragma unroll
        for (int nt = 0; nt < 3; ++nt) acc[mt][nt] = (f32x4){0.f, 0.f, 0.f, 0.f};

    #pragma unroll
    for (int nt = 0; nt < 3; ++nt) {
        bf16x8 wf[4];                          // A-operand: weight rows [n][k]
        #pragma unroll
        for (int ks = 0; ks < 4; ++ks)
            wf[ks] = *(const bf16x8*)&Bs[nw + nt * 16 + n16][ks * 32 + quad * 8];
        #pragma unroll
        for (int ks = 0; ks < 4; ++ks)
            #pragma unroll
            for (int mt = 0; mt < 2; ++mt)
                acc[mt][nt] = __builtin_amdgcn_mfma_f32_16x16x32_bf16(wf[ks], pf[mt][ks], acc[mt][nt], 0, 0, 0);
    }

    #pragma unroll
    for (int nt = 0; nt < 3; ++nt) {
        int nbase = n0 + nw + nt * 16 + quad * 4;
        float4 b4 = *(const float4*)(bias + nbase);
        float sc = (nbase < CC) ? QSC : 1.0f;  // group of 4 never straddles 128
        #pragma unroll
        for (int mt = 0; mt < 2; ++mt) {
            int m = m0 + mw + mt * 16 + n16;
            __hip_bfloat162 h01 = __float22bfloat162_rn(float2{(acc[mt][nt][0] + b4.x) * sc, (acc[mt][nt][1] + b4.y) * sc});
            __hip_bfloat162 h23 = __float22bfloat162_rn(float2{(acc[mt][nt][2] + b4.z) * sc, (acc[mt][nt][3] + b4.w) * sc});
            uint2 pk;
            pk.x = *(unsigned int*)&h01;
            pk.y = *(unsigned int*)&h23;
            *(uint2*)&out[(size_t)m * 384 + nbase] = pk;
        }
    }
}

// ---------------------------------------------------------------------------
// K2: MFMA attention, S^T formulation, 512 threads (8 waves).
//   Key change vs prev: the 16 bias float4s are loaded INTO s[16] (they are
//   the MFMA C-operands) in a separate unrolled loop BEFORE the MFMA chain,
//   so all 16 global loads pipeline instead of serializing one vmcnt stall
//   per MFMA (prev VGPR_Count=60 proved they were not hoisted).
//   Staging now uses all 512 threads (half K-row + 16 V^T elems each).
//   exp2 via raw v_exp_f32 builtin. setprio(1) around MFMA clusters.
// ---------------------------------------------------------------------------
__global__ __launch_bounds__(512, 4) void attn_mfma_kernel(
    const __hip_bfloat16* __restrict__ qkv,   // [65536,384]
    const float* __restrict__ biasM,          // [256,256] *log2e
    __hip_bfloat16* __restrict__ attn_out)    // [65536,128]
{
    __shared__ __align__(16) __hip_bfloat16 Ks[NN][40];      // 20.0 KB
    __shared__ __align__(16) __hip_bfloat16 VTs[DD][264];    // 16.5 KB
    __shared__ __align__(16) __hip_bfloat16 Ps[8][16][136];  // 34.0 KB (k-half)

    const int bi = blockIdx.x;
    const int i = bi >> 2, h = bi & 3;
    const int t = threadIdx.x;

    {   // stage K rows + V^T with ALL 512 threads: r = t>>1, half = t&1
        const int r = t >> 1, half = t & 1;
        const __hip_bfloat16* base = qkv + (size_t)(i * NN + r) * 384 + h * DD;
        const u128* ksrc = (const u128*)(base + CC) + half * 2;
        u128* kdst = (u128*)&Ks[r][0] + half * 2;
        kdst[0] = ksrc[0];
        kdst[1] = ksrc[1];
        const u128* vsrc = (const u128*)(base + 2 * CC) + half * 2;
        u128 vr[2];
        vr[0] = vsrc[0];
        vr[1] = vsrc[1];
        const __hip_bfloat16* vh = (const __hip_bfloat16*)vr;
        #pragma unroll
        for (int dd = 0; dd < 16; ++dd) VTs[half * 16 + dd][r] = vh[dd];
    }
    __syncthreads();

    const int w = t >> 6, lane = t & 63;
    const int n16 = lane & 15, quad = lane >> 4;

    for (int jt = 0; jt < 2; ++jt) {
        const int j0 = w * 32 + jt * 16;
        const int j = j0 + n16;                // this lane's softmax column

        // Q B-frag for row j
        bf16x8 qa = *(const bf16x8*)(qkv + (size_t)(i * NN + j) * 384 + h * DD + quad * 8);
        const float4* brow = (const float4*)(biasM + (size_t)j * NN);

        // bias rides in the accumulator registers: batch all 16 loads first
        f32x4 s[16];
        #pragma unroll
        for (int kt = 0; kt < 16; ++kt) {
            float4 b4 = brow[kt * 4 + quad];
            s[kt] = (f32x4){b4.x, b4.y, b4.z, b4.w};
        }
        // S^T tiles: s[kt][r] = S[k=kt*16+quad*4+r][j]  (in-place C->D)
        __builtin_amdgcn_s_setprio(1);
        #pragma unroll
        for (int kt = 0; kt < 16; ++kt) {
            bf16x8 kb = *(const bf16x8*)&Ks[kt * 16 + n16][quad * 8];
            s[kt] = __builtin_amdgcn_mfma_f32_16x16x32_bf16(kb, qa, s[kt], 0, 0, 0);
        }
        __builtin_amdgcn_s_setprio(0);

        // raw exp2 (no max) + packed P write, two k-halves; PV across passes
        f32x4 sm = {0.f, 0.f, 0.f, 0.f};
        f32x4 o[2] = {(f32x4){0.f, 0.f, 0.f, 0.f}, (f32x4){0.f, 0.f, 0.f, 0.f}};
        #pragma unroll
        for (int pass = 0; pass < 2; ++pass) {
            #pragma unroll
            for (int kt8 = 0; kt8 < 8; ++kt8) {
                int kt = pass * 8 + kt8;
                float p0 = __builtin_amdgcn_exp2f(s[kt][0]);
                float p1 = __builtin_amdgcn_exp2f(s[kt][1]);
                float p2 = __builtin_amdgcn_exp2f(s[kt][2]);
                float p3 = __builtin_amdgcn_exp2f(s[kt][3]);
                sm[0] += p0; sm[1] += p1; sm[2] += p2; sm[3] += p3;
                __hip_bfloat162 h01 = __float22bfloat162_rn(float2{p0, p1});
                __hip_bfloat162 h23 = __float22bfloat162_rn(float2{p2, p3});
                uint2 pk;
                pk.x = *(unsigned int*)&h01;
                pk.y = *(unsigned int*)&h23;
                *(uint2*)&Ps[w][n16][kt8 * 16 + quad * 4] = pk;
            }
            // PV for this k-half (per-wave in-order LDS: reads see the writes)
            __builtin_amdgcn_s_setprio(1);
            #pragma unroll
            for (int c = 0; c < 4; ++c) {
                bf16x8 pa = *(const bf16x8*)&Ps[w][n16][c * 32 + quad * 8];
                #pragma unroll
                for (int dt = 0; dt < 2; ++dt) {
                    bf16x8 vb = *(const bf16x8*)&VTs[dt * 16 + n16][pass * 128 + c * 32 + quad * 8];
                    o[dt] = __builtin_amdgcn_mfma_f32_16x16x32_bf16(vb, pa, o[dt], 0, 0, 0);
                }
            }
            __builtin_amdgcn_s_setprio(0);
        }
        float sum = (sm[0] + sm[1]) + (sm[2] + sm[3]);
        sum += __shfl_xor(sum, 16);
        sum += __shfl_xor(sum, 32);
        float inv = 1.0f / sum;

        // store: column j (same lane as softmax -> own inv), packed d
        __hip_bfloat16* obase = attn_out + (size_t)(i * NN + j) * CC + h * DD + quad * 4;
        #pragma unroll
        for (int dt = 0; dt < 2; ++dt) {
            __hip_bfloat162 h01 = __float22bfloat162_rn(float2{o[dt][0] * inv, o[dt][1] * inv});
            __hip_bfloat162 h23 = __float22bfloat162_rn(float2{o[dt][2] * inv, o[dt][3] * inv});
            uint2 pk;
            pk.x = *(unsigned int*)&h01;
            pk.y = *(unsigned int*)&h23;
            *(uint2*)(obase + dt * 16) = pk;
        }
    }
}

// ---------------------------------------------------------------------------
// K3: out = attn_out @ Wout + bout  (MFMA, operand-swapped -> float4 stores)
// 512 threads (8 waves): mw=(w&3)*32, nw=(w>>2)*64; 2mt x 4nt x 4k = 32 MFMAs.
// ---------------------------------------------------------------------------
__global__ __launch_bounds__(512, 4) void out_mfma_kernel(
    const __hip_bfloat16* __restrict__ A,     // [65536,128] bf16
    const __hip_bfloat16* __restrict__ Bt,    // [128,128] bf16 (transposed W)
    const float* __restrict__ bias,           // [128]
    float* __restrict__ out)                  // [65536,128]
{
    __shared__ __align__(16) __hip_bfloat16 As[128][136];
    __shared__ __align__(16) __hip_bfloat16 Bs[128][136];
    const int t = threadIdx.x;
    const int m0 = blockIdx.x * 128;

    #pragma unroll
    for (int it = 0; it < 4; ++it) {
        int idx = it * 512 + t;
        int r = idx >> 4, c8 = (idx & 15) * 8;
        *(u128*)&As[r][c8] = *(const u128*)(A + (size_t)(m0 + r) * CC + c8);
    }
    #pragma unroll
    for (int it = 0; it < 4; ++it) {
        int idx = it * 512 + t;
        int n = idx >> 4, c8 = (idx & 15) * 8;
        *(u128*)&Bs[n][c8] = *(const u128*)(Bt + (size_t)n * CC + c8);
    }
    __syncthreads();

    const int w = t >> 6, lane = t & 63;
    const int n16 = lane & 15, quad = lane >> 4;
    const int mw = (w & 3) * 32, nw = (w >> 2) * 64;

    bf16x8 pf[2][4];
    #pragma unroll
    for (int mt = 0; mt < 2; ++mt)
        #pragma unroll
        for (int ks = 0; ks < 4; ++ks)
            pf[mt][ks] = *(const bf16x8*)&As[mw + mt * 16 + n16][ks * 32 + quad * 8];

    f32x4 acc[2][4];
    #pragma unroll
    for (int mt = 0; mt < 2; ++mt)
        #pragma unroll
        for (int nt = 0; nt < 4; ++nt) acc[mt][nt] = (f32x4){0.f, 0.f, 0.f, 0.f};

    #pragma unroll
    for (int nt = 0; nt < 4; ++nt) {
        bf16x8 wf[4];
        #pragma unroll
        for (int ks = 0; ks < 4; ++ks)
            wf[ks] = *(const bf16x8*)&Bs[nw + nt * 16 + n16][ks * 32 + quad * 8];
        #pragma unroll
        for (int ks = 0; ks < 4; ++ks)
            #pragma unroll
            for (int mt = 0; mt < 2; ++mt)
                acc[mt][nt] = __builtin_amdgcn_mfma_f32_16x16x32_bf16(wf[ks], pf[mt][ks], acc[mt][nt], 0, 0, 0);
    }

    #pragma unroll
    for (int nt = 0; nt < 4; ++nt) {
        int nbase = nw + nt * 16 + quad * 4;
        float4 b4 = *(const float4*)(bias + nbase);
        #pragma unroll
        for (int mt = 0; mt < 2; ++mt) {
            int m = m0 + mw + mt * 16 + n16;
            float4 ov;
            ov.x = acc[mt][nt][0] + b4.x;
            ov.y = acc[mt][nt][1] + b4.y;
            ov.z = acc[mt][nt][2] + b4.z;
            ov.w = acc[mt][nt][3] + b4.w;
            *(float4*)&out[(size_t)m * CC + nbase] = ov;
        }
    }
}

// ---------------------------------------------------------------------------
extern "C" void kernel_launch(void* const* d_in, const int* in_sizes, int n_in,
                              void* d_out, int out_size, void* d_ws, size_t ws_size,
                              hipStream_t stream) {
    const float* pair_rep = (const float*)d_in[0];
    const float* dm       = (const float*)d_in[1];
    const float* Wqkv     = (const float*)d_in[2];
    const float* bqkv     = (const float*)d_in[3];
    const float* Wout     = (const float*)d_in[4];
    const float* bout     = (const float*)d_in[5];
    const float* dscale   = (const float*)d_in[6];
    const int*   mask     = (const int*)d_in[7];
    float* out = (float*)d_out;

    // ws: biasM[256KB] | Wt_qkv[96KB] | Wt_out[32KB] | qkv[48MB] | attn[16MB]
    // Abf (bf16 pair_rep, 16MB) ALIASES the attn buffer: prep writes it,
    // qkv reads it, then attn_mfma overwrites the region (stream-ordered).
    char* p = (char*)d_ws;
    float* biasM = (float*)p;                 p += (size_t)NN * NN * 4;
    __hip_bfloat16* Wt_qkv = (__hip_bfloat16*)p;  p += (size_t)384 * CC * 2;
    __hip_bfloat16* Wt_out = (__hip_bfloat16*)p;  p += (size_t)CC * CC * 2;
    __hip_bfloat16* qkv  = (__hip_bfloat16*)p;    p += (size_t)65536 * 384 * 2;
    __hip_bfloat16* attn = (__hip_bfloat16*)p;
    __hip_bfloat16* Abf  = attn;              // alias (see above)

    prep_kernel<<<dim3(4608), dim3(256), 0, stream>>>(dm, mask, dscale, Wqkv, Wout, pair_rep, biasM, Wt_qkv, Wt_out, Abf);
    qkv_mfma_kernel<<<dim3(512, 4), dim3(512), 0, stream>>>(Abf, Wt_qkv, bqkv, qkv);
    attn_mfma_kernel<<<dim3(1024), dim3(512), 0, stream>>>(qkv, biasM, attn);
    out_mfma_kernel<<<dim3(512), dim3(512), 0, stream>>>(attn, Wt_out, bout, out);
}

// Round 2
// 168.095 us; speedup vs baseline: 1.0430x; 1.0097x over previous
//
#include <hip/hip_runtime.h>
#include <hip/hip_bf16.h>
#include <math.h>

#define NN 256
#define CC 128
#define HH 4
#define DD 32

typedef uint4 u128;
typedef __bf16 bf16x8 __attribute__((ext_vector_type(8)));
typedef float f32x4 __attribute__((ext_vector_type(4)));

#define LOG2E 1.4426950408889634f
#define QSC (0.17677669529663687f * LOG2E)   // 1/sqrt(32) * log2(e), folded into q

// ---------------------------------------------------------------------------
// K0 prep: biasM[j][k] = (mask[j][k] ? -inf : dscale*dm[j][k]) * log2e
//          Wt_qkv[n][k] = bf16(Wqkv[k][n]); Wt_out[n][k] = bf16(Wout[k][n])
//          Abf = bf16(pair_rep)   (so K1 stages bf16 directly, no per-block cvt)
// ---------------------------------------------------------------------------
__global__ __launch_bounds__(256) void prep_kernel(
    const float* __restrict__ dm, const int* __restrict__ mask,
    const float* __restrict__ dscale,
    const float* __restrict__ Wqkv, const float* __restrict__ Wout,
    const float* __restrict__ pair,
    float* __restrict__ biasM,
    __hip_bfloat16* __restrict__ Wt_qkv, __hip_bfloat16* __restrict__ Wt_out,
    __hip_bfloat16* __restrict__ Abf)
{
    const int b = blockIdx.x, t = threadIdx.x;
    if (b < 256) {
        int idx = b * 256 + t;                 // coalesced both sides
        biasM[idx] = mask[idx] ? -INFINITY : dscale[0] * dm[idx] * LOG2E;
    } else if (b < 448) {
        int idx = (b - 256) * 256 + t;         // [0, 49152)
        int n = idx >> 7, k = idx & 127;
        Wt_qkv[idx] = __float2bfloat16(Wqkv[(size_t)k * 384 + n]);
    } else if (b < 512) {
        int idx = (b - 448) * 256 + t;         // [0, 16384)
        int n = idx >> 7, k = idx & 127;
        Wt_out[idx] = __float2bfloat16(Wout[(size_t)k * CC + n]);
    } else {
        // pair_rep fp32 -> bf16, 8 elems/thread, 4096 blocks
        size_t e = (size_t)(b - 512) * 2048 + (size_t)t * 8;
        float4 v0 = *(const float4*)(pair + e);
        float4 v1 = *(const float4*)(pair + e + 4);
        __hip_bfloat162 a01 = __float22bfloat162_rn(float2{v0.x, v0.y});
        __hip_bfloat162 a23 = __float22bfloat162_rn(float2{v0.z, v0.w});
        __hip_bfloat162 a45 = __float22bfloat162_rn(float2{v1.x, v1.y});
        __hip_bfloat162 a67 = __float22bfloat162_rn(float2{v1.z, v1.w});
        u128 pk;
        pk.x = *(unsigned int*)&a01;
        pk.y = *(unsigned int*)&a23;
        pk.z = *(unsigned int*)&a45;
        pk.w = *(unsigned int*)&a67;
        *(u128*)&Abf[e] = pk;
    }
}

// ---------------------------------------------------------------------------
// K1: qkv = pair_rep @ Wqkv + bqkv  (MFMA, operand-swapped: C[n][m])
// A arrives pre-converted bf16 -> staging is 4x u128 copies (half the bytes,
// no VALU convert). 512 threads (8 waves); per-wave 2mt x 3nt x 4k = 24 MFMAs.
// q columns (n<128) pre-scaled by QSC for the attention exp2 path.
// ---------------------------------------------------------------------------
__global__ __launch_bounds__(512, 4) void qkv_mfma_kernel(
    const __hip_bfloat16* __restrict__ A,     // [65536,128] bf16
    const __hip_bfloat16* __restrict__ Bt,    // [384,128] bf16 (transposed W)
    const float* __restrict__ bias,           // [384]
    __hip_bfloat16* __restrict__ out)         // [65536,384]
{
    __shared__ __align__(16) __hip_bfloat16 As[128][136];
    __shared__ __align__(16) __hip_bfloat16 Bs[96][136];
    const int t = threadIdx.x;
    const int m0 = blockIdx.x * 128;
    const int n0 = blockIdx.y * 96;

    #pragma unroll
    for (int it = 0; it < 4; ++it) {           // A: bf16 u128 copies
        int idx = it * 512 + t;
        int r = idx >> 4, c8 = (idx & 15) * 8;
        *(u128*)&As[r][c8] = *(const u128*)(A + (size_t)(m0 + r) * CC + c8);
    }
    #pragma unroll
    for (int it = 0; it < 3; ++it) {
        int idx = it * 512 + t;
        int n = idx >> 4, c8 = (idx & 15) * 8;
        *(u128*)&Bs[n][c8] = *(const u128*)(Bt + (size_t)(n0 + n) * CC + c8);
    }
    __syncthreads();

    const int w = t >> 6, lane = t & 63;
    const int n16 = lane & 15, quad = lane >> 4;
    const int mw = (w & 3) * 32, nw = (w >> 2) * 48;

    bf16x8 pf[2][4];                           // B-operand: pair rows [m][k]
    #pragma unroll
    for (int mt = 0; mt < 2; ++mt)
        #pragma unroll
        for (int ks = 0; ks < 4; ++ks)
            pf[mt][ks] = *(const bf16x8*)&As[mw + mt * 16 + n16][ks * 32 + quad * 8];

    f32x4 acc[2][3];
    #pragma unroll
    for (int mt = 0; mt < 2; ++mt)
        #pragma unroll
        for (int nt = 0; nt < 3; ++nt) acc[mt][nt] = (f32x4){0.f, 0.f, 0.f, 0.f};

    #pragma unroll
    for (int nt = 0; nt < 3; ++nt) {
        bf16x8 wf[4];                          // A-operand: weight rows [n][k]
        #pragma unroll
        for (int ks = 0; ks < 4; ++ks)
            wf[ks] = *(const bf16x8*)&Bs[nw + nt * 16 + n16][ks * 32 + quad * 8];
        #pragma unroll
        for (int ks = 0; ks < 4; ++ks)
            #pragma unroll
            for (int mt = 0; mt < 2; ++mt)
                acc[mt][nt] = __builtin_amdgcn_mfma_f32_16x16x32_bf16(wf[ks], pf[mt][ks], acc[mt][nt], 0, 0, 0);
    }

    #pragma unroll
    for (int nt = 0; nt < 3; ++nt) {
        int nbase = n0 + nw + nt * 16 + quad * 4;
        float4 b4 = *(const float4*)(bias + nbase);
        float sc = (nbase < CC) ? QSC : 1.0f;  // group of 4 never straddles 128
        #pragma unroll
        for (int mt = 0; mt < 2; ++mt) {
            int m = m0 + mw + mt * 16 + n16;
            __hip_bfloat162 h01 = __float22bfloat162_rn(float2{(acc[mt][nt][0] + b4.x) * sc, (acc[mt][nt][1] + b4.y) * sc});
            __hip_bfloat162 h23 = __float22bfloat162_rn(float2{(acc[mt][nt][2] + b4.z) * sc, (acc[mt][nt][3] + b4.w) * sc});
            uint2 pk;
            pk.x = *(unsigned int*)&h01;
            pk.y = *(unsigned int*)&h23;
            *(uint2*)&out[(size_t)m * 384 + nbase] = pk;
        }
    }
}

// ---------------------------------------------------------------------------
// K2: MFMA attention, S^T formulation, 512 threads (8 waves).
//   Key change vs prev: the 16 bias float4 loads are issued via inline-asm
//   global_load_dwordx4 directly into the s[16] accumulators, so ALL 16 are
//   in flight simultaneously (prev round: compiler re-sank them, VGPR stayed
//   60, one serialized L2 round-trip per MFMA). One s_waitcnt vmcnt(0) +
//   sched_barrier(0) (rule #18) before the MFMA chain.
// ---------------------------------------------------------------------------
__global__ __launch_bounds__(512, 4) void attn_mfma_kernel(
    const __hip_bfloat16* __restrict__ qkv,   // [65536,384]
    const float* __restrict__ biasM,          // [256,256] *log2e
    __hip_bfloat16* __restrict__ attn_out)    // [65536,128]
{
    __shared__ __align__(16) __hip_bfloat16 Ks[NN][40];      // 20.0 KB
    __shared__ __align__(16) __hip_bfloat16 VTs[DD][264];    // 16.5 KB
    __shared__ __align__(16) __hip_bfloat16 Ps[8][16][136];  // 34.0 KB (k-half)

    const int bi = blockIdx.x;
    const int i = bi >> 2, h = bi & 3;
    const int t = threadIdx.x;

    {   // stage K rows + V^T with ALL 512 threads: r = t>>1, half = t&1
        const int r = t >> 1, half = t & 1;
        const __hip_bfloat16* base = qkv + (size_t)(i * NN + r) * 384 + h * DD;
        const u128* ksrc = (const u128*)(base + CC) + half * 2;
        u128* kdst = (u128*)&Ks[r][0] + half * 2;
        kdst[0] = ksrc[0];
        kdst[1] = ksrc[1];
        const u128* vsrc = (const u128*)(base + 2 * CC) + half * 2;
        u128 vr[2];
        vr[0] = vsrc[0];
        vr[1] = vsrc[1];
        const __hip_bfloat16* vh = (const __hip_bfloat16*)vr;
        #pragma unroll
        for (int dd = 0; dd < 16; ++dd) VTs[half * 16 + dd][r] = vh[dd];
    }
    __syncthreads();

    const int w = t >> 6, lane = t & 63;
    const int n16 = lane & 15, quad = lane >> 4;

    for (int jt = 0; jt < 2; ++jt) {
        const int j0 = w * 32 + jt * 16;
        const int j = j0 + n16;                // this lane's softmax column

        // Q B-frag for row j (issues first, drains with the same vmcnt(0))
        bf16x8 qa = *(const bf16x8*)(qkv + (size_t)(i * NN + j) * 384 + h * DD + quad * 8);

        // bias rides in the accumulator registers: FORCE all 16 loads in
        // flight via inline asm (compiler refuses to hold 64 live VGPRs).
        const float* bp = biasM + (size_t)j * NN + quad * 4;
        f32x4 s[16];
        #pragma unroll
        for (int kt = 0; kt < 16; ++kt) {
            asm volatile("global_load_dwordx4 %0, %1, off offset:%2"
                         : "=v"(s[kt]) : "v"(bp), "i"(kt * 64));
        }
        asm volatile("s_waitcnt vmcnt(0)" ::: "memory");
        __builtin_amdgcn_sched_barrier(0);

        // S^T tiles: s[kt][r] = S[k=kt*16+quad*4+r][j]  (in-place C->D)
        __builtin_amdgcn_s_setprio(1);
        #pragma unroll
        for (int kt = 0; kt < 16; ++kt) {
            bf16x8 kb = *(const bf16x8*)&Ks[kt * 16 + n16][quad * 8];
            s[kt] = __builtin_amdgcn_mfma_f32_16x16x32_bf16(kb, qa, s[kt], 0, 0, 0);
        }
        __builtin_amdgcn_s_setprio(0);

        // raw exp2 (no max) + packed P write, two k-halves; PV across passes
        f32x4 sm = {0.f, 0.f, 0.f, 0.f};
        f32x4 o[2] = {(f32x4){0.f, 0.f, 0.f, 0.f}, (f32x4){0.f, 0.f, 0.f, 0.f}};
        #pragma unroll
        for (int pass = 0; pass < 2; ++pass) {
            #pragma unroll
            for (int kt8 = 0; kt8 < 8; ++kt8) {
                int kt = pass * 8 + kt8;
                float p0 = __builtin_amdgcn_exp2f(s[kt][0]);
                float p1 = __builtin_amdgcn_exp2f(s[kt][1]);
                float p2 = __builtin_amdgcn_exp2f(s[kt][2]);
                float p3 = __builtin_amdgcn_exp2f(s[kt][3]);
                sm[0] += p0; sm[1] += p1; sm[2] += p2; sm[3] += p3;
                __hip_bfloat162 h01 = __float22bfloat162_rn(float2{p0, p1});
                __hip_bfloat162 h23 = __float22bfloat162_rn(float2{p2, p3});
                uint2 pk;
                pk.x = *(unsigned int*)&h01;
                pk.y = *(unsigned int*)&h23;
                *(uint2*)&Ps[w][n16][kt8 * 16 + quad * 4] = pk;
            }
            // PV for this k-half (per-wave in-order LDS: reads see the writes)
            __builtin_amdgcn_s_setprio(1);
            #pragma unroll
            for (int c = 0; c < 4; ++c) {
                bf16x8 pa = *(const bf16x8*)&Ps[w][n16][c * 32 + quad * 8];
                #pragma unroll
                for (int dt = 0; dt < 2; ++dt) {
                    bf16x8 vb = *(const bf16x8*)&VTs[dt * 16 + n16][pass * 128 + c * 32 + quad * 8];
                    o[dt] = __builtin_amdgcn_mfma_f32_16x16x32_bf16(vb, pa, o[dt], 0, 0, 0);
                }
            }
            __builtin_amdgcn_s_setprio(0);
        }
        float sum = (sm[0] + sm[1]) + (sm[2] + sm[3]);
        sum += __shfl_xor(sum, 16);
        sum += __shfl_xor(sum, 32);
        float inv = 1.0f / sum;

        // store: column j (same lane as softmax -> own inv), packed d
        __hip_bfloat16* obase = attn_out + (size_t)(i * NN + j) * CC + h * DD + quad * 4;
        #pragma unroll
        for (int dt = 0; dt < 2; ++dt) {
            __hip_bfloat162 h01 = __float22bfloat162_rn(float2{o[dt][0] * inv, o[dt][1] * inv});
            __hip_bfloat162 h23 = __float22bfloat162_rn(float2{o[dt][2] * inv, o[dt][3] * inv});
            uint2 pk;
            pk.x = *(unsigned int*)&h01;
            pk.y = *(unsigned int*)&h23;
            *(uint2*)(obase + dt * 16) = pk;
        }
    }
}

// ---------------------------------------------------------------------------
// K3: out = attn_out @ Wout + bout  (MFMA, operand-swapped -> float4 stores)
// 512 threads (8 waves): mw=(w&3)*32, nw=(w>>2)*64; 2mt x 4nt x 4k = 32 MFMAs.
// ---------------------------------------------------------------------------
__global__ __launch_bounds__(512, 4) void out_mfma_kernel(
    const __hip_bfloat16* __restrict__ A,     // [65536,128] bf16
    const __hip_bfloat16* __restrict__ Bt,    // [128,128] bf16 (transposed W)
    const float* __restrict__ bias,           // [128]
    float* __restrict__ out)                  // [65536,128]
{
    __shared__ __align__(16) __hip_bfloat16 As[128][136];
    __shared__ __align__(16) __hip_bfloat16 Bs[128][136];
    const int t = threadIdx.x;
    const int m0 = blockIdx.x * 128;

    #pragma unroll
    for (int it = 0; it < 4; ++it) {
        int idx = it * 512 + t;
        int r = idx >> 4, c8 = (idx & 15) * 8;
        *(u128*)&As[r][c8] = *(const u128*)(A + (size_t)(m0 + r) * CC + c8);
    }
    #pragma unroll
    for (int it = 0; it < 4; ++it) {
        int idx = it * 512 + t;
        int n = idx >> 4, c8 = (idx & 15) * 8;
        *(u128*)&Bs[n][c8] = *(const u128*)(Bt + (size_t)n * CC + c8);
    }
    __syncthreads();

    const int w = t >> 6, lane = t & 63;
    const int n16 = lane & 15, quad = lane >> 4;
    const int mw = (w & 3) * 32, nw = (w >> 2) * 64;

    bf16x8 pf[2][4];
    #pragma unroll
    for (int mt = 0; mt < 2; ++mt)
        #pragma unroll
        for (int ks = 0; ks < 4; ++ks)
            pf[mt][ks] = *(const bf16x8*)&As[mw + mt * 16 + n16][ks * 32 + quad * 8];

    f32x4 acc[2][4];
    #pragma unroll
    for (int mt = 0; mt < 2; ++mt)
        #pragma unroll
        for (int nt = 0; nt < 4; ++nt) acc[mt][nt] = (f32x4){0.f, 0.f, 0.f, 0.f};

    #pragma unroll
    for (int nt = 0; nt < 4; ++nt) {
        bf16x8 wf[4];
        #pragma unroll
        for (int ks = 0; ks < 4; ++ks)
            wf[ks] = *(const bf16x8*)&Bs[nw + nt * 16 + n16][ks * 32 + quad * 8];
        #pragma unroll
        for (int ks = 0; ks < 4; ++ks)
            #pragma unroll
            for (int mt = 0; mt < 2; ++mt)
                acc[mt][nt] = __builtin_amdgcn_mfma_f32_16x16x32_bf16(wf[ks], pf[mt][ks], acc[mt][nt], 0, 0, 0);
    }

    #pragma unroll
    for (int nt = 0; nt < 4; ++nt) {
        int nbase = nw + nt * 16 + quad * 4;
        float4 b4 = *(const float4*)(bias + nbase);
        #pragma unroll
        for (int mt = 0; mt < 2; ++mt) {
            int m = m0 + mw + mt * 16 + n16;
            float4 ov;
            ov.x = acc[mt][nt][0] + b4.x;
            ov.y = acc[mt][nt][1] + b4.y;
            ov.z = acc[mt][nt][2] + b4.z;
            ov.w = acc[mt][nt][3] + b4.w;
            *(float4*)&out[(size_t)m * CC + nbase] = ov;
        }
    }
}

// ---------------------------------------------------------------------------
extern "C" void kernel_launch(void* const* d_in, const int* in_sizes, int n_in,
                              void* d_out, int out_size, void* d_ws, size_t ws_size,
                              hipStream_t stream) {
    const float* pair_rep = (const float*)d_in[0];
    const float* dm       = (const float*)d_in[1];
    const float* Wqkv     = (const float*)d_in[2];
    const float* bqkv     = (const float*)d_in[3];
    const float* Wout     = (const float*)d_in[4];
    const float* bout     = (const float*)d_in[5];
    const float* dscale   = (const float*)d_in[6];
    const int*   mask     = (const int*)d_in[7];
    float* out = (float*)d_out;

    // ws: biasM[256KB] | Wt_qkv[96KB] | Wt_out[32KB] | qkv[48MB] | attn[16MB]
    // Abf (bf16 pair_rep, 16MB) ALIASES the attn buffer: prep writes it,
    // qkv reads it, then attn_mfma overwrites the region (stream-ordered).
    char* p = (char*)d_ws;
    float* biasM = (float*)p;                 p += (size_t)NN * NN * 4;
    __hip_bfloat16* Wt_qkv = (__hip_bfloat16*)p;  p += (size_t)384 * CC * 2;
    __hip_bfloat16* Wt_out = (__hip_bfloat16*)p;  p += (size_t)CC * CC * 2;
    __hip_bfloat16* qkv  = (__hip_bfloat16*)p;    p += (size_t)65536 * 384 * 2;
    __hip_bfloat16* attn = (__hip_bfloat16*)p;
    __hip_bfloat16* Abf  = attn;              // alias (see above)

    prep_kernel<<<dim3(4608), dim3(256), 0, stream>>>(dm, mask, dscale, Wqkv, Wout, pair_rep, biasM, Wt_qkv, Wt_out, Abf);
    qkv_mfma_kernel<<<dim3(512, 4), dim3(512), 0, stream>>>(Abf, Wt_qkv, bqkv, qkv);
    attn_mfma_kernel<<<dim3(1024), dim3(512), 0, stream>>>(qkv, biasM, attn);
    out_mfma_kernel<<<dim3(512), dim3(512), 0, stream>>>(attn, Wt_out, bout, out);
}

// Round 3
// 167.210 us; speedup vs baseline: 1.0485x; 1.0053x over previous
//
#include <hip/hip_runtime.h>
#include <hip/hip_bf16.h>
#include <math.h>

#define NN 256
#define CC 128
#define HH 4
#define DD 32

typedef uint4 u128;
typedef __bf16 bf16x8 __attribute__((ext_vector_type(8)));
typedef float f32x4 __attribute__((ext_vector_type(4)));

#define LOG2E 1.4426950408889634f
#define QSC (0.17677669529663687f * LOG2E)   // 1/sqrt(32) * log2(e), folded into q

// ---------------------------------------------------------------------------
// K0 prep: biasM[j][k] = (mask[j][k] ? -inf : dscale*dm[j][k]) * log2e
//          Wt_qkv[n][k] = bf16(Wqkv[k][n]); Wt_out[n][k] = bf16(Wout[k][n])
//          Abf = bf16(pair_rep)
// ---------------------------------------------------------------------------
__global__ __launch_bounds__(256) void prep_kernel(
    const float* __restrict__ dm, const int* __restrict__ mask,
    const float* __restrict__ dscale,
    const float* __restrict__ Wqkv, const float* __restrict__ Wout,
    const float* __restrict__ pair,
    float* __restrict__ biasM,
    __hip_bfloat16* __restrict__ Wt_qkv, __hip_bfloat16* __restrict__ Wt_out,
    __hip_bfloat16* __restrict__ Abf)
{
    const int b = blockIdx.x, t = threadIdx.x;
    if (b < 256) {
        int idx = b * 256 + t;                 // coalesced both sides
        biasM[idx] = mask[idx] ? -INFINITY : dscale[0] * dm[idx] * LOG2E;
    } else if (b < 448) {
        int idx = (b - 256) * 256 + t;         // [0, 49152)
        int n = idx >> 7, k = idx & 127;
        Wt_qkv[idx] = __float2bfloat16(Wqkv[(size_t)k * 384 + n]);
    } else if (b < 512) {
        int idx = (b - 448) * 256 + t;         // [0, 16384)
        int n = idx >> 7, k = idx & 127;
        Wt_out[idx] = __float2bfloat16(Wout[(size_t)k * CC + n]);
    } else {
        // pair_rep fp32 -> bf16, 8 elems/thread, 4096 blocks
        size_t e = (size_t)(b - 512) * 2048 + (size_t)t * 8;
        float4 v0 = *(const float4*)(pair + e);
        float4 v1 = *(const float4*)(pair + e + 4);
        __hip_bfloat162 a01 = __float22bfloat162_rn(float2{v0.x, v0.y});
        __hip_bfloat162 a23 = __float22bfloat162_rn(float2{v0.z, v0.w});
        __hip_bfloat162 a45 = __float22bfloat162_rn(float2{v1.x, v1.y});
        __hip_bfloat162 a67 = __float22bfloat162_rn(float2{v1.z, v1.w});
        u128 pk;
        pk.x = *(unsigned int*)&a01;
        pk.y = *(unsigned int*)&a23;
        pk.z = *(unsigned int*)&a45;
        pk.w = *(unsigned int*)&a67;
        *(u128*)&Abf[e] = pk;
    }
}

// ---------------------------------------------------------------------------
// K1: qkv = pair_rep @ Wqkv + bqkv  (MFMA, operand-swapped: C[n][m])
// ---------------------------------------------------------------------------
__global__ __launch_bounds__(512, 4) void qkv_mfma_kernel(
    const __hip_bfloat16* __restrict__ A,     // [65536,128] bf16
    const __hip_bfloat16* __restrict__ Bt,    // [384,128] bf16 (transposed W)
    const float* __restrict__ bias,           // [384]
    __hip_bfloat16* __restrict__ out)         // [65536,384]
{
    __shared__ __align__(16) __hip_bfloat16 As[128][136];
    __shared__ __align__(16) __hip_bfloat16 Bs[96][136];
    const int t = threadIdx.x;
    const int m0 = blockIdx.x * 128;
    const int n0 = blockIdx.y * 96;

    #pragma unroll
    for (int it = 0; it < 4; ++it) {           // A: bf16 u128 copies
        int idx = it * 512 + t;
        int r = idx >> 4, c8 = (idx & 15) * 8;
        *(u128*)&As[r][c8] = *(const u128*)(A + (size_t)(m0 + r) * CC + c8);
    }
    #pragma unroll
    for (int it = 0; it < 3; ++it) {
        int idx = it * 512 + t;
        int n = idx >> 4, c8 = (idx & 15) * 8;
        *(u128*)&Bs[n][c8] = *(const u128*)(Bt + (size_t)(n0 + n) * CC + c8);
    }
    __syncthreads();

    const int w = t >> 6, lane = t & 63;
    const int n16 = lane & 15, quad = lane >> 4;
    const int mw = (w & 3) * 32, nw = (w >> 2) * 48;

    bf16x8 pf[2][4];                           // B-operand: pair rows [m][k]
    #pragma unroll
    for (int mt = 0; mt < 2; ++mt)
        #pragma unroll
        for (int ks = 0; ks < 4; ++ks)
            pf[mt][ks] = *(const bf16x8*)&As[mw + mt * 16 + n16][ks * 32 + quad * 8];

    f32x4 acc[2][3];
    #pragma unroll
    for (int mt = 0; mt < 2; ++mt)
        #pragma unroll
        for (int nt = 0; nt < 3; ++nt) acc[mt][nt] = (f32x4){0.f, 0.f, 0.f, 0.f};

    #pragma unroll
    for (int nt = 0; nt < 3; ++nt) {
        bf16x8 wf[4];                          // A-operand: weight rows [n][k]
        #pragma unroll
        for (int ks = 0; ks < 4; ++ks)
            wf[ks] = *(const bf16x8*)&Bs[nw + nt * 16 + n16][ks * 32 + quad * 8];
        #pragma unroll
        for (int ks = 0; ks < 4; ++ks)
            #pragma unroll
            for (int mt = 0; mt < 2; ++mt)
                acc[mt][nt] = __builtin_amdgcn_mfma_f32_16x16x32_bf16(wf[ks], pf[mt][ks], acc[mt][nt], 0, 0, 0);
    }

    #pragma unroll
    for (int nt = 0; nt < 3; ++nt) {
        int nbase = n0 + nw + nt * 16 + quad * 4;
        float4 b4 = *(const float4*)(bias + nbase);
        float sc = (nbase < CC) ? QSC : 1.0f;  // group of 4 never straddles 128
        #pragma unroll
        for (int mt = 0; mt < 2; ++mt) {
            int m = m0 + mw + mt * 16 + n16;
            __hip_bfloat162 h01 = __float22bfloat162_rn(float2{(acc[mt][nt][0] + b4.x) * sc, (acc[mt][nt][1] + b4.y) * sc});
            __hip_bfloat162 h23 = __float22bfloat162_rn(float2{(acc[mt][nt][2] + b4.z) * sc, (acc[mt][nt][3] + b4.w) * sc});
            uint2 pk;
            pk.x = *(unsigned int*)&h01;
            pk.y = *(unsigned int*)&h23;
            *(uint2*)&out[(size_t)m * 384 + nbase] = pk;
        }
    }
}

// ---------------------------------------------------------------------------
// K2: MFMA attention, S^T formulation, 512 threads (8 waves).
//   RESTRUCTURED: the P LDS buffer (34 KB) is ELIMINATED. The S-MFMA D-layout
//   leaves lane (quad,n16) holding P at k = 32c + 16b + 4*quad + r; the PV
//   B-frag wants position 32c + 8*quad + 4b + r. Sum over k is permutation-
//   invariant, so V's k-rows are staged PERMUTED (k-bit swizzle
//   [4][3:2][1:0] -> [3:2]->[4:3], [4]->[2]) and exp2'd scores pack straight
//   into the PV B-operand in registers. LDS 72->37 KB => 4 blocks/CU,
//   all 1024 blocks co-resident, 8 waves/SIMD (launch_bounds(512,8)).
//   Streaming per-32-k-window chain keeps <=2 S tiles live (reg-lean).
// ---------------------------------------------------------------------------
__global__ __launch_bounds__(512, 8) void attn_mfma_kernel(
    const __hip_bfloat16* __restrict__ qkv,   // [65536,384]
    const float* __restrict__ biasM,          // [256,256] *log2e
    __hip_bfloat16* __restrict__ attn_out)    // [65536,128]
{
    __shared__ __align__(16) __hip_bfloat16 Ks[NN][40];      // 20.0 KB
    __shared__ __align__(16) __hip_bfloat16 VTs[DD][264];    // 16.5 KB

    const int bi = blockIdx.x;
    const int i = bi >> 2, h = bi & 3;
    const int t = threadIdx.x;

    {   // stage K rows + permuted V^T with ALL 512 threads
        const int r = t >> 1, half = t & 1;
        const __hip_bfloat16* base = qkv + (size_t)(i * NN + r) * 384 + h * DD;
        const u128* ksrc = (const u128*)(base + CC) + half * 2;
        u128* kdst = (u128*)&Ks[r][0] + half * 2;
        kdst[0] = ksrc[0];
        kdst[1] = ksrc[1];
        const u128* vsrc = (const u128*)(base + 2 * CC) + half * 2;
        u128 vr[2];
        vr[0] = vsrc[0];
        vr[1] = vsrc[1];
        const __hip_bfloat16* vh = (const __hip_bfloat16*)vr;
        // k-bit swizzle: k = [b4|q1 q0|r1 r0] -> pos = [q1 q0|b4|r1 r0]
        const int pr = (r & ~0x1F) | ((r & 0xC) << 1) | ((r & 0x10) >> 2) | (r & 0x3);
        #pragma unroll
        for (int dd = 0; dd < 16; ++dd) VTs[half * 16 + dd][pr] = vh[dd];
    }
    __syncthreads();

    const int w = t >> 6, lane = t & 63;
    const int n16 = lane & 15, quad = lane >> 4;

    #pragma unroll
    for (int jt = 0; jt < 2; ++jt) {
        const int j0 = w * 32 + jt * 16;
        const int j = j0 + n16;                // this lane's softmax column

        // Q B-frag for row j
        bf16x8 qa = *(const bf16x8*)(qkv + (size_t)(i * NN + j) * 384 + h * DD + quad * 8);
        const float4* brow = (const float4*)(biasM + (size_t)j * NN);

        f32x4 sm = {0.f, 0.f, 0.f, 0.f};
        f32x4 o0 = {0.f, 0.f, 0.f, 0.f}, o1 = {0.f, 0.f, 0.f, 0.f};

        #pragma unroll 2
        for (int c = 0; c < 8; ++c) {
            // bias rides the MFMA C-operand (k = 32c+4q+r and 32c+16+4q+r)
            float4 b0 = brow[c * 8 + quad];
            float4 b1 = brow[c * 8 + 4 + quad];
            bf16x8 kb0 = *(const bf16x8*)&Ks[c * 32 + n16][quad * 8];
            bf16x8 kb1 = *(const bf16x8*)&Ks[c * 32 + 16 + n16][quad * 8];
            f32x4 s0 = __builtin_amdgcn_mfma_f32_16x16x32_bf16(
                kb0, qa, (f32x4){b0.x, b0.y, b0.z, b0.w}, 0, 0, 0);
            f32x4 s1 = __builtin_amdgcn_mfma_f32_16x16x32_bf16(
                kb1, qa, (f32x4){b1.x, b1.y, b1.z, b1.w}, 0, 0, 0);

            float p0 = __builtin_amdgcn_exp2f(s0[0]);
            float p1 = __builtin_amdgcn_exp2f(s0[1]);
            float p2 = __builtin_amdgcn_exp2f(s0[2]);
            float p3 = __builtin_amdgcn_exp2f(s0[3]);
            float p4 = __builtin_amdgcn_exp2f(s1[0]);
            float p5 = __builtin_amdgcn_exp2f(s1[1]);
            float p6 = __builtin_amdgcn_exp2f(s1[2]);
            float p7 = __builtin_amdgcn_exp2f(s1[3]);
            sm[0] += p0 + p4;
            sm[1] += p1 + p5;
            sm[2] += p2 + p6;
            sm[3] += p3 + p7;

            // pack straight into the PV B-frag (V was staged permuted)
            __hip_bfloat162 q01 = __float22bfloat162_rn(float2{p0, p1});
            __hip_bfloat162 q23 = __float22bfloat162_rn(float2{p2, p3});
            __hip_bfloat162 q45 = __float22bfloat162_rn(float2{p4, p5});
            __hip_bfloat162 q67 = __float22bfloat162_rn(float2{p6, p7});
            u128 pk;
            pk.x = *(unsigned int*)&q01;
            pk.y = *(unsigned int*)&q23;
            pk.z = *(unsigned int*)&q45;
            pk.w = *(unsigned int*)&q67;
            bf16x8 pa = *(bf16x8*)&pk;

            bf16x8 vb0 = *(const bf16x8*)&VTs[n16][c * 32 + quad * 8];
            bf16x8 vb1 = *(const bf16x8*)&VTs[16 + n16][c * 32 + quad * 8];
            o0 = __builtin_amdgcn_mfma_f32_16x16x32_bf16(vb0, pa, o0, 0, 0, 0);
            o1 = __builtin_amdgcn_mfma_f32_16x16x32_bf16(vb1, pa, o1, 0, 0, 0);
        }

        float sum = (sm[0] + sm[1]) + (sm[2] + sm[3]);
        sum += __shfl_xor(sum, 16);
        sum += __shfl_xor(sum, 32);
        float inv = 1.0f / sum;

        // store: column j (same lane as softmax -> own inv), packed d
        __hip_bfloat16* obase = attn_out + (size_t)(i * NN + j) * CC + h * DD + quad * 4;
        {
            __hip_bfloat162 h01 = __float22bfloat162_rn(float2{o0[0] * inv, o0[1] * inv});
            __hip_bfloat162 h23 = __float22bfloat162_rn(float2{o0[2] * inv, o0[3] * inv});
            uint2 pk;
            pk.x = *(unsigned int*)&h01;
            pk.y = *(unsigned int*)&h23;
            *(uint2*)(obase) = pk;
        }
        {
            __hip_bfloat162 h01 = __float22bfloat162_rn(float2{o1[0] * inv, o1[1] * inv});
            __hip_bfloat162 h23 = __float22bfloat162_rn(float2{o1[2] * inv, o1[3] * inv});
            uint2 pk;
            pk.x = *(unsigned int*)&h01;
            pk.y = *(unsigned int*)&h23;
            *(uint2*)(obase + 16) = pk;
        }
    }
}

// ---------------------------------------------------------------------------
// K3: out = attn_out @ Wout + bout  (MFMA, operand-swapped -> float4 stores)
// ---------------------------------------------------------------------------
__global__ __launch_bounds__(512, 4) void out_mfma_kernel(
    const __hip_bfloat16* __restrict__ A,     // [65536,128] bf16
    const __hip_bfloat16* __restrict__ Bt,    // [128,128] bf16 (transposed W)
    const float* __restrict__ bias,           // [128]
    float* __restrict__ out)                  // [65536,128]
{
    __shared__ __align__(16) __hip_bfloat16 As[128][136];
    __shared__ __align__(16) __hip_bfloat16 Bs[128][136];
    const int t = threadIdx.x;
    const int m0 = blockIdx.x * 128;

    #pragma unroll
    for (int it = 0; it < 4; ++it) {
        int idx = it * 512 + t;
        int r = idx >> 4, c8 = (idx & 15) * 8;
        *(u128*)&As[r][c8] = *(const u128*)(A + (size_t)(m0 + r) * CC + c8);
    }
    #pragma unroll
    for (int it = 0; it < 4; ++it) {
        int idx = it * 512 + t;
        int n = idx >> 4, c8 = (idx & 15) * 8;
        *(u128*)&Bs[n][c8] = *(const u128*)(Bt + (size_t)n * CC + c8);
    }
    __syncthreads();

    const int w = t >> 6, lane = t & 63;
    const int n16 = lane & 15, quad = lane >> 4;
    const int mw = (w & 3) * 32, nw = (w >> 2) * 64;

    bf16x8 pf[2][4];
    #pragma unroll
    for (int mt = 0; mt < 2; ++mt)
        #pragma unroll
        for (int ks = 0; ks < 4; ++ks)
            pf[mt][ks] = *(const bf16x8*)&As[mw + mt * 16 + n16][ks * 32 + quad * 8];

    f32x4 acc[2][4];
    #pragma unroll
    for (int mt = 0; mt < 2; ++mt)
        #pragma unroll
        for (int nt = 0; nt < 4; ++nt) acc[mt][nt] = (f32x4){0.f, 0.f, 0.f, 0.f};

    #pragma unroll
    for (int nt = 0; nt < 4; ++nt) {
        bf16x8 wf[4];
        #pragma unroll
        for (int ks = 0; ks < 4; ++ks)
            wf[ks] = *(const bf16x8*)&Bs[nw + nt * 16 + n16][ks * 32 + quad * 8];
        #pragma unroll
        for (int ks = 0; ks < 4; ++ks)
            #pragma unroll
            for (int mt = 0; mt < 2; ++mt)
                acc[mt][nt] = __builtin_amdgcn_mfma_f32_16x16x32_bf16(wf[ks], pf[mt][ks], acc[mt][nt], 0, 0, 0);
    }

    #pragma unroll
    for (int nt = 0; nt < 4; ++nt) {
        int nbase = nw + nt * 16 + quad * 4;
        float4 b4 = *(const float4*)(bias + nbase);
        #pragma unroll
        for (int mt = 0; mt < 2; ++mt) {
            int m = m0 + mw + mt * 16 + n16;
            float4 ov;
            ov.x = acc[mt][nt][0] + b4.x;
            ov.y = acc[mt][nt][1] + b4.y;
            ov.z = acc[mt][nt][2] + b4.z;
            ov.w = acc[mt][nt][3] + b4.w;
            *(float4*)&out[(size_t)m * CC + nbase] = ov;
        }
    }
}

// ---------------------------------------------------------------------------
extern "C" void kernel_launch(void* const* d_in, const int* in_sizes, int n_in,
                              void* d_out, int out_size, void* d_ws, size_t ws_size,
                              hipStream_t stream) {
    const float* pair_rep = (const float*)d_in[0];
    const float* dm       = (const float*)d_in[1];
    const float* Wqkv     = (const float*)d_in[2];
    const float* bqkv     = (const float*)d_in[3];
    const float* Wout     = (const float*)d_in[4];
    const float* bout     = (const float*)d_in[5];
    const float* dscale   = (const float*)d_in[6];
    const int*   mask     = (const int*)d_in[7];
    float* out = (float*)d_out;

    // ws: biasM[256KB] | Wt_qkv[96KB] | Wt_out[32KB] | qkv[48MB] | attn[16MB]
    // Abf (bf16 pair_rep, 16MB) ALIASES the attn buffer: prep writes it,
    // qkv reads it, then attn_mfma overwrites the region (stream-ordered).
    char* p = (char*)d_ws;
    float* biasM = (float*)p;                 p += (size_t)NN * NN * 4;
    __hip_bfloat16* Wt_qkv = (__hip_bfloat16*)p;  p += (size_t)384 * CC * 2;
    __hip_bfloat16* Wt_out = (__hip_bfloat16*)p;  p += (size_t)CC * CC * 2;
    __hip_bfloat16* qkv  = (__hip_bfloat16*)p;    p += (size_t)65536 * 384 * 2;
    __hip_bfloat16* attn = (__hip_bfloat16*)p;
    __hip_bfloat16* Abf  = attn;              // alias (see above)

    prep_kernel<<<dim3(4608), dim3(256), 0, stream>>>(dm, mask, dscale, Wqkv, Wout, pair_rep, biasM, Wt_qkv, Wt_out, Abf);
    qkv_mfma_kernel<<<dim3(512, 4), dim3(512), 0, stream>>>(Abf, Wt_qkv, bqkv, qkv);
    attn_mfma_kernel<<<dim3(1024), dim3(512), 0, stream>>>(qkv, biasM, attn);
    out_mfma_kernel<<<dim3(512), dim3(512), 0, stream>>>(attn, Wt_out, bout, out);
}

// Round 5
// 160.789 us; speedup vs baseline: 1.0904x; 1.0399x over previous
//
#include <hip/hip_runtime.h>
#include <hip/hip_bf16.h>
#include <math.h>

#define NN 256
#define CC 128
#define HH 4
#define DD 32

typedef uint4 u128;
typedef __bf16 bf16x8 __attribute__((ext_vector_type(8)));
typedef float f32x4 __attribute__((ext_vector_type(4)));

#define LOG2E 1.4426950408889634f
#define QSC (0.17677669529663687f * LOG2E)   // 1/sqrt(32) * log2(e), folded into q

// ---------------------------------------------------------------------------
// K0 prep: bias2 = PERMUTED bias layout so attn's per-lane bias loads are
//          fully coalesced:
//            bias2_f4[((c*2+b)*16 + j>>4)*64 + quad*16 + (j&15)][r]
//              = (mask[j][k] ? -inf : dscale*dm[j][k]) * log2e
//            where k = c*32 + b*16 + quad*4 + r.
//          Wt_qkv[n][k] = bf16(Wqkv[k][n]); Wt_out[n][k] = bf16(Wout[k][n])
// ---------------------------------------------------------------------------
__global__ __launch_bounds__(256) void prep_kernel(
    const float* __restrict__ dm, const int* __restrict__ mask,
    const float* __restrict__ dscale,
    const float* __restrict__ Wqkv, const float* __restrict__ Wout,
    float* __restrict__ bias2,
    __hip_bfloat16* __restrict__ Wt_qkv, __hip_bfloat16* __restrict__ Wt_out)
{
    const int b = blockIdx.x, t = threadIdx.x;
    if (b < 256) {
        const int j = b, k = t;               // coalesced source read
        int idx = j * 256 + k;
        float v = mask[idx] ? -INFINITY : dscale[0] * dm[idx] * LOG2E;
        int c = k >> 5, bb = (k >> 4) & 1, quad = (k >> 2) & 3, r = k & 3;
        int dst = ((((c * 2 + bb) * 16 + (j >> 4)) * 64) + quad * 16 + (j & 15)) * 4 + r;
        bias2[dst] = v;
    } else if (b < 448) {
        int idx = (b - 256) * 256 + t;         // [0, 49152)
        int n = idx >> 7, k = idx & 127;
        Wt_qkv[idx] = __float2bfloat16(Wqkv[(size_t)k * 384 + n]);
    } else {
        int idx = (b - 448) * 256 + t;         // [0, 16384)
        int n = idx >> 7, k = idx & 127;
        Wt_out[idx] = __float2bfloat16(Wout[(size_t)k * CC + n]);
    }
}

// ---------------------------------------------------------------------------
// K1: qkv = pair_rep @ Wqkv + bqkv  (MFMA, operand-swapped: C[n][m])
// A is fp32; converted to bf16 during LDS staging (no Abf round-trip:
// pre-converting cost 32 MB extra HBM traffic, measured net-negative).
// ---------------------------------------------------------------------------
__global__ __launch_bounds__(512, 4) void qkv_mfma_kernel(
    const float* __restrict__ A,              // [65536,128] fp32
    const __hip_bfloat16* __restrict__ Bt,    // [384,128] bf16 (transposed W)
    const float* __restrict__ bias,           // [384]
    __hip_bfloat16* __restrict__ out)         // [65536,384]
{
    __shared__ __align__(16) __hip_bfloat16 As[128][136];
    __shared__ __align__(16) __hip_bfloat16 Bs[96][136];
    const int t = threadIdx.x;
    const int m0 = blockIdx.x * 128;
    const int n0 = blockIdx.y * 96;

    #pragma unroll
    for (int it = 0; it < 8; ++it) {           // A: fp32 -> bf16 into LDS
        int idx = it * 512 + t;
        int r = idx >> 5, c4 = (idx & 31) * 4;
        float4 v = *(const float4*)(A + (size_t)(m0 + r) * CC + c4);
        __hip_bfloat162 a01 = __float22bfloat162_rn(float2{v.x, v.y});
        __hip_bfloat162 a23 = __float22bfloat162_rn(float2{v.z, v.w});
        uint2 pk;
        pk.x = *(unsigned int*)&a01;
        pk.y = *(unsigned int*)&a23;
        *(uint2*)&As[r][c4] = pk;
    }
    #pragma unroll
    for (int it = 0; it < 3; ++it) {
        int idx = it * 512 + t;
        int n = idx >> 4, c8 = (idx & 15) * 8;
        *(u128*)&Bs[n][c8] = *(const u128*)(Bt + (size_t)(n0 + n) * CC + c8);
    }
    __syncthreads();

    const int w = t >> 6, lane = t & 63;
    const int n16 = lane & 15, quad = lane >> 4;
    const int mw = (w & 3) * 32, nw = (w >> 2) * 48;

    bf16x8 pf[2][4];                           // B-operand: pair rows [m][k]
    #pragma unroll
    for (int mt = 0; mt < 2; ++mt)
        #pragma unroll
        for (int ks = 0; ks < 4; ++ks)
            pf[mt][ks] = *(const bf16x8*)&As[mw + mt * 16 + n16][ks * 32 + quad * 8];

    f32x4 acc[2][3];
    #pragma unroll
    for (int mt = 0; mt < 2; ++mt)
        #pragma unroll
        for (int nt = 0; nt < 3; ++nt) acc[mt][nt] = (f32x4){0.f, 0.f, 0.f, 0.f};

    #pragma unroll
    for (int nt = 0; nt < 3; ++nt) {
        bf16x8 wf[4];                          // A-operand: weight rows [n][k]
        #pragma unroll
        for (int ks = 0; ks < 4; ++ks)
            wf[ks] = *(const bf16x8*)&Bs[nw + nt * 16 + n16][ks * 32 + quad * 8];
        #pragma unroll
        for (int ks = 0; ks < 4; ++ks)
            #pragma unroll
            for (int mt = 0; mt < 2; ++mt)
                acc[mt][nt] = __builtin_amdgcn_mfma_f32_16x16x32_bf16(wf[ks], pf[mt][ks], acc[mt][nt], 0, 0, 0);
    }

    #pragma unroll
    for (int nt = 0; nt < 3; ++nt) {
        int nbase = n0 + nw + nt * 16 + quad * 4;
        float4 b4 = *(const float4*)(bias + nbase);
        float sc = (nbase < CC) ? QSC : 1.0f;  // group of 4 never straddles 128
        #pragma unroll
        for (int mt = 0; mt < 2; ++mt) {
            int m = m0 + mw + mt * 16 + n16;
            __hip_bfloat162 h01 = __float22bfloat162_rn(float2{(acc[mt][nt][0] + b4.x) * sc, (acc[mt][nt][1] + b4.y) * sc});
            __hip_bfloat162 h23 = __float22bfloat162_rn(float2{(acc[mt][nt][2] + b4.z) * sc, (acc[mt][nt][3] + b4.w) * sc});
            uint2 pk;
            pk.x = *(unsigned int*)&h01;
            pk.y = *(unsigned int*)&h23;
            *(uint2*)&out[(size_t)m * 384 + nbase] = pk;
        }
    }
}

// ---------------------------------------------------------------------------
// K2: MFMA attention, S^T formulation, 512 threads (8 waves).
//   Bias loads are now COALESCED: prep pre-permuted biasM into bias2 so each
//   wave's per-(c,b) bias read is bias2_f4[((c*2+b)*16+jblk)*64 + lane] —
//   one contiguous 1 KB transaction instead of a 16-row gather (prev: every
//   float4 load = 16 scattered 64B lines; 32 waves/CU of those saturated the
//   TA/L1 queue -> invariant 44 us across three structures).
//   V staged k-permuted so exp2'd P packs straight into the PV B-frag.
// ---------------------------------------------------------------------------
__global__ __launch_bounds__(512, 8) void attn_mfma_kernel(
    const __hip_bfloat16* __restrict__ qkv,   // [65536,384]
    const float* __restrict__ bias2,          // [256,256] permuted, *log2e
    __hip_bfloat16* __restrict__ attn_out)    // [65536,128]
{
    __shared__ __align__(16) __hip_bfloat16 Ks[NN][40];      // 20.0 KB
    __shared__ __align__(16) __hip_bfloat16 VTs[DD][264];    // 16.5 KB

    const int bi = blockIdx.x;
    const int i = bi >> 2, h = bi & 3;
    const int t = threadIdx.x;

    {   // stage K rows + permuted V^T with ALL 512 threads
        const int r = t >> 1, half = t & 1;
        const __hip_bfloat16* base = qkv + (size_t)(i * NN + r) * 384 + h * DD;
        const u128* ksrc = (const u128*)(base + CC) + half * 2;
        u128* kdst = (u128*)&Ks[r][0] + half * 2;
        kdst[0] = ksrc[0];
        kdst[1] = ksrc[1];
        const u128* vsrc = (const u128*)(base + 2 * CC) + half * 2;
        u128 vr[2];
        vr[0] = vsrc[0];
        vr[1] = vsrc[1];
        const __hip_bfloat16* vh = (const __hip_bfloat16*)vr;
        // k-bit swizzle: k = [b4|q1 q0|r1 r0] -> pos = [q1 q0|b4|r1 r0]
        const int pr = (r & ~0x1F) | ((r & 0xC) << 1) | ((r & 0x10) >> 2) | (r & 0x3);
        #pragma unroll
        for (int dd = 0; dd < 16; ++dd) VTs[half * 16 + dd][pr] = vh[dd];
    }
    __syncthreads();

    const int w = t >> 6, lane = t & 63;
    const int n16 = lane & 15, quad = lane >> 4;

    #pragma unroll
    for (int jt = 0; jt < 2; ++jt) {
        const int j0 = w * 32 + jt * 16;
        const int j = j0 + n16;                // this lane's softmax column
        const int jblk = w * 2 + jt;           // j0 >> 4

        // Q B-frag for row j
        bf16x8 qa = *(const bf16x8*)(qkv + (size_t)(i * NN + j) * 384 + h * DD + quad * 8);
        const float4* bb = (const float4*)bias2;

        f32x4 sm = {0.f, 0.f, 0.f, 0.f};
        f32x4 o0 = {0.f, 0.f, 0.f, 0.f}, o1 = {0.f, 0.f, 0.f, 0.f};

        #pragma unroll 2
        for (int c = 0; c < 8; ++c) {
            // bias rides the MFMA C-operand; loads are lane-contiguous now
            float4 b0 = bb[((c * 2 + 0) * 16 + jblk) * 64 + lane];
            float4 b1 = bb[((c * 2 + 1) * 16 + jblk) * 64 + lane];
            bf16x8 kb0 = *(const bf16x8*)&Ks[c * 32 + n16][quad * 8];
            bf16x8 kb1 = *(const bf16x8*)&Ks[c * 32 + 16 + n16][quad * 8];
            f32x4 s0 = __builtin_amdgcn_mfma_f32_16x16x32_bf16(
                kb0, qa, (f32x4){b0.x, b0.y, b0.z, b0.w}, 0, 0, 0);
            f32x4 s1 = __builtin_amdgcn_mfma_f32_16x16x32_bf16(
                kb1, qa, (f32x4){b1.x, b1.y, b1.z, b1.w}, 0, 0, 0);

            float p0 = __builtin_amdgcn_exp2f(s0[0]);
            float p1 = __builtin_amdgcn_exp2f(s0[1]);
            float p2 = __builtin_amdgcn_exp2f(s0[2]);
            float p3 = __builtin_amdgcn_exp2f(s0[3]);
            float p4 = __builtin_amdgcn_exp2f(s1[0]);
            float p5 = __builtin_amdgcn_exp2f(s1[1]);
            float p6 = __builtin_amdgcn_exp2f(s1[2]);
            float p7 = __builtin_amdgcn_exp2f(s1[3]);
            sm[0] += p0 + p4;
            sm[1] += p1 + p5;
            sm[2] += p2 + p6;
            sm[3] += p3 + p7;

            // pack straight into the PV B-frag (V was staged permuted)
            __hip_bfloat162 q01 = __float22bfloat162_rn(float2{p0, p1});
            __hip_bfloat162 q23 = __float22bfloat162_rn(float2{p2, p3});
            __hip_bfloat162 q45 = __float22bfloat162_rn(float2{p4, p5});
            __hip_bfloat162 q67 = __float22bfloat162_rn(float2{p6, p7});
            u128 pk;
            pk.x = *(unsigned int*)&q01;
            pk.y = *(unsigned int*)&q23;
            pk.z = *(unsigned int*)&q45;
            pk.w = *(unsigned int*)&q67;
            bf16x8 pa = *(bf16x8*)&pk;

            bf16x8 vb0 = *(const bf16x8*)&VTs[n16][c * 32 + quad * 8];
            bf16x8 vb1 = *(const bf16x8*)&VTs[16 + n16][c * 32 + quad * 8];
            o0 = __builtin_amdgcn_mfma_f32_16x16x32_bf16(vb0, pa, o0, 0, 0, 0);
            o1 = __builtin_amdgcn_mfma_f32_16x16x32_bf16(vb1, pa, o1, 0, 0, 0);
        }

        float sum = (sm[0] + sm[1]) + (sm[2] + sm[3]);
        sum += __shfl_xor(sum, 16);
        sum += __shfl_xor(sum, 32);
        float inv = 1.0f / sum;

        // store: column j (same lane as softmax -> own inv), packed d
        __hip_bfloat16* obase = attn_out + (size_t)(i * NN + j) * CC + h * DD + quad * 4;
        {
            __hip_bfloat162 h01 = __float22bfloat162_rn(float2{o0[0] * inv, o0[1] * inv});
            __hip_bfloat162 h23 = __float22bfloat162_rn(float2{o0[2] * inv, o0[3] * inv});
            uint2 pk;
            pk.x = *(unsigned int*)&h01;
            pk.y = *(unsigned int*)&h23;
            *(uint2*)(obase) = pk;
        }
        {
            __hip_bfloat162 h01 = __float22bfloat162_rn(float2{o1[0] * inv, o1[1] * inv});
            __hip_bfloat162 h23 = __float22bfloat162_rn(float2{o1[2] * inv, o1[3] * inv});
            uint2 pk;
            pk.x = *(unsigned int*)&h01;
            pk.y = *(unsigned int*)&h23;
            *(uint2*)(obase + 16) = pk;
        }
    }
}

// ---------------------------------------------------------------------------
// K3: out = attn_out @ Wout + bout  (MFMA, operand-swapped -> float4 stores)
// ---------------------------------------------------------------------------
__global__ __launch_bounds__(512, 4) void out_mfma_kernel(
    const __hip_bfloat16* __restrict__ A,     // [65536,128] bf16
    const __hip_bfloat16* __restrict__ Bt,    // [128,128] bf16 (transposed W)
    const float* __restrict__ bias,           // [128]
    float* __restrict__ out)                  // [65536,128]
{
    __shared__ __align__(16) __hip_bfloat16 As[128][136];
    __shared__ __align__(16) __hip_bfloat16 Bs[128][136];
    const int t = threadIdx.x;
    const int m0 = blockIdx.x * 128;

    #pragma unroll
    for (int it = 0; it < 4; ++it) {
        int idx = it * 512 + t;
        int r = idx >> 4, c8 = (idx & 15) * 8;
        *(u128*)&As[r][c8] = *(const u128*)(A + (size_t)(m0 + r) * CC + c8);
    }
    #pragma unroll
    for (int it = 0; it < 4; ++it) {
        int idx = it * 512 + t;
        int n = idx >> 4, c8 = (idx & 15) * 8;
        *(u128*)&Bs[n][c8] = *(const u128*)(Bt + (size_t)n * CC + c8);
    }
    __syncthreads();

    const int w = t >> 6, lane = t & 63;
    const int n16 = lane & 15, quad = lane >> 4;
    const int mw = (w & 3) * 32, nw = (w >> 2) * 64;

    bf16x8 pf[2][4];
    #pragma unroll
    for (int mt = 0; mt < 2; ++mt)
        #pragma unroll
        for (int ks = 0; ks < 4; ++ks)
            pf[mt][ks] = *(const bf16x8*)&As[mw + mt * 16 + n16][ks * 32 + quad * 8];

    f32x4 acc[2][4];
    #pragma unroll
    for (int mt = 0; mt < 2; ++mt)
        #pragma unroll
        for (int nt = 0; nt < 4; ++nt) acc[mt][nt] = (f32x4){0.f, 0.f, 0.f, 0.f};

    #pragma unroll
    for (int nt = 0; nt < 4; ++nt) {
        bf16x8 wf[4];
        #pragma unroll
        for (int ks = 0; ks < 4; ++ks)
            wf[ks] = *(const bf16x8*)&Bs[nw + nt * 16 + n16][ks * 32 + quad * 8];
        #pragma unroll
        for (int ks = 0; ks < 4; ++ks)
            #pragma unroll
            for (int mt = 0; mt < 2; ++mt)
                acc[mt][nt] = __builtin_amdgcn_mfma_f32_16x16x32_bf16(wf[ks], pf[mt][ks], acc[mt][nt], 0, 0, 0);
    }

    #pragma unroll
    for (int nt = 0; nt < 4; ++nt) {
        int nbase = nw + nt * 16 + quad * 4;
        float4 b4 = *(const float4*)(bias + nbase);
        #pragma unroll
        for (int mt = 0; mt < 2; ++mt) {
            int m = m0 + mw + mt * 16 + n16;
            float4 ov;
            ov.x = acc[mt][nt][0] + b4.x;
            ov.y = acc[mt][nt][1] + b4.y;
            ov.z = acc[mt][nt][2] + b4.z;
            ov.w = acc[mt][nt][3] + b4.w;
            *(float4*)&out[(size_t)m * CC + nbase] = ov;
        }
    }
}

// ---------------------------------------------------------------------------
extern "C" void kernel_launch(void* const* d_in, const int* in_sizes, int n_in,
                              void* d_out, int out_size, void* d_ws, size_t ws_size,
                              hipStream_t stream) {
    const float* pair_rep = (const float*)d_in[0];
    const float* dm       = (const float*)d_in[1];
    const float* Wqkv     = (const float*)d_in[2];
    const float* bqkv     = (const float*)d_in[3];
    const float* Wout     = (const float*)d_in[4];
    const float* bout     = (const float*)d_in[5];
    const float* dscale   = (const float*)d_in[6];
    const int*   mask     = (const int*)d_in[7];
    float* out = (float*)d_out;

    // ws: bias2[256KB] | Wt_qkv[96KB] | Wt_out[32KB] | qkv[48MB] | attn[16MB]
    char* p = (char*)d_ws;
    float* bias2 = (float*)p;                 p += (size_t)NN * NN * 4;
    __hip_bfloat16* Wt_qkv = (__hip_bfloat16*)p;  p += (size_t)384 * CC * 2;
    __hip_bfloat16* Wt_out = (__hip_bfloat16*)p;  p += (size_t)CC * CC * 2;
    __hip_bfloat16* qkv  = (__hip_bfloat16*)p;    p += (size_t)65536 * 384 * 2;
    __hip_bfloat16* attn = (__hip_bfloat16*)p;

    prep_kernel<<<dim3(512), dim3(256), 0, stream>>>(dm, mask, dscale, Wqkv, Wout, bias2, Wt_qkv, Wt_out);
    qkv_mfma_kernel<<<dim3(512, 4), dim3(512), 0, stream>>>(pair_rep, Wt_qkv, bqkv, qkv);
    attn_mfma_kernel<<<dim3(1024), dim3(512), 0, stream>>>(qkv, bias2, attn);
    out_mfma_kernel<<<dim3(512), dim3(512), 0, stream>>>(attn, Wt_out, bout, out);
}

// Round 6
// 146.400 us; speedup vs baseline: 1.1976x; 1.0983x over previous
//
#include <hip/hip_runtime.h>
#include <hip/hip_bf16.h>
#include <math.h>

#define NN 256
#define CC 128
#define HH 4
#define DD 32

typedef uint4 u128;
typedef __bf16 bf16x8 __attribute__((ext_vector_type(8)));
typedef float f32x4 __attribute__((ext_vector_type(4)));

#define LOG2E 1.4426950408889634f
#define QSC (0.17677669529663687f * LOG2E)   // 1/sqrt(32) * log2(e), folded into q

// ---------------------------------------------------------------------------
// K0 prep: bias2 = PERMUTED bias layout so attn's per-lane bias loads are
//          fully coalesced (see attn kernel comment).
//          Wt_qkv[n][k] = bf16(Wqkv[k][n]); Wt_out[n][k] = bf16(Wout[k][n])
// ---------------------------------------------------------------------------
__global__ __launch_bounds__(256) void prep_kernel(
    const float* __restrict__ dm, const int* __restrict__ mask,
    const float* __restrict__ dscale,
    const float* __restrict__ Wqkv, const float* __restrict__ Wout,
    float* __restrict__ bias2,
    __hip_bfloat16* __restrict__ Wt_qkv, __hip_bfloat16* __restrict__ Wt_out)
{
    const int b = blockIdx.x, t = threadIdx.x;
    if (b < 256) {
        const int j = b, k = t;               // coalesced source read
        int idx = j * 256 + k;
        float v = mask[idx] ? -INFINITY : dscale[0] * dm[idx] * LOG2E;
        int c = k >> 5, bb = (k >> 4) & 1, quad = (k >> 2) & 3, r = k & 3;
        int dst = ((((c * 2 + bb) * 16 + (j >> 4)) * 64) + quad * 16 + (j & 15)) * 4 + r;
        bias2[dst] = v;
    } else if (b < 448) {
        int idx = (b - 256) * 256 + t;         // [0, 49152)
        int n = idx >> 7, k = idx & 127;
        Wt_qkv[idx] = __float2bfloat16(Wqkv[(size_t)k * 384 + n]);
    } else {
        int idx = (b - 448) * 256 + t;         // [0, 16384)
        int n = idx >> 7, k = idx & 127;
        Wt_out[idx] = __float2bfloat16(Wout[(size_t)k * CC + n]);
    }
}

// ---------------------------------------------------------------------------
// K1: qkv = pair_rep @ Wqkv + bqkv  (MFMA, operand-swapped: C[n][m])
// RESTRUCTURED: grid 512 blocks (one per 128-row A tile). A is staged ONCE
// (batch: 8 float4 loads in flight -> convert -> LDS), pf fragments loaded
// once, then an internal loop over the 4 96-col B chunks re-stages only the
// 25.5 KB Bs (L2-hot: all blocks read the same 96 KB Wt_qkv). B-restage
// loads are issued BEFORE the epilogue stores so stores cover the latency.
// LDS 59.5 KB -> 2 blocks/CU -> all 512 blocks co-resident (zero tail).
// Previous: 512x4 grid re-staged + re-converted the same A tile 4x.
// ---------------------------------------------------------------------------
__global__ __launch_bounds__(512, 2) void qkv_mfma_kernel(
    const float* __restrict__ A,              // [65536,128] fp32
    const __hip_bfloat16* __restrict__ Bt,    // [384,128] bf16 (transposed W)
    const float* __restrict__ bias,           // [384]
    __hip_bfloat16* __restrict__ out)         // [65536,384]
{
    __shared__ __align__(16) __hip_bfloat16 As[128][136];
    __shared__ __align__(16) __hip_bfloat16 Bs[96][136];
    const int t = threadIdx.x;
    const int m0 = blockIdx.x * 128;

    // A: batch all 8 global loads into registers (in flight together),
    // then convert+write. Compiler can't re-sink: regs consumed in loop 2.
    float4 va[8];
    #pragma unroll
    for (int it = 0; it < 8; ++it) {
        int idx = it * 512 + t;
        int r = idx >> 5, c4 = (idx & 31) * 4;
        va[it] = *(const float4*)(A + (size_t)(m0 + r) * CC + c4);
    }
    #pragma unroll
    for (int it = 0; it < 8; ++it) {
        int idx = it * 512 + t;
        int r = idx >> 5, c4 = (idx & 31) * 4;
        __hip_bfloat162 a01 = __float22bfloat162_rn(float2{va[it].x, va[it].y});
        __hip_bfloat162 a23 = __float22bfloat162_rn(float2{va[it].z, va[it].w});
        uint2 pk;
        pk.x = *(unsigned int*)&a01;
        pk.y = *(unsigned int*)&a23;
        *(uint2*)&As[r][c4] = pk;
    }
    #pragma unroll
    for (int it = 0; it < 3; ++it) {           // B chunk 0
        int idx = it * 512 + t;
        int n = idx >> 4, c8 = (idx & 15) * 8;
        *(u128*)&Bs[n][c8] = *(const u128*)(Bt + (size_t)n * CC + c8);
    }
    __syncthreads();

    const int w = t >> 6, lane = t & 63;
    const int n16 = lane & 15, quad = lane >> 4;
    const int mw = (w & 3) * 32, nw = (w >> 2) * 48;

    bf16x8 pf[2][4];                           // B-operand: pair rows [m][k] — once
    #pragma unroll
    for (int mt = 0; mt < 2; ++mt)
        #pragma unroll
        for (int ks = 0; ks < 4; ++ks)
            pf[mt][ks] = *(const bf16x8*)&As[mw + mt * 16 + n16][ks * 32 + quad * 8];

    for (int nc = 0; nc < 4; ++nc) {
        const int n0 = nc * 96;

        f32x4 acc[2][3];
        #pragma unroll
        for (int mt = 0; mt < 2; ++mt)
            #pragma unroll
            for (int nt = 0; nt < 3; ++nt) acc[mt][nt] = (f32x4){0.f, 0.f, 0.f, 0.f};

        #pragma unroll
        for (int nt = 0; nt < 3; ++nt) {
            bf16x8 wf[4];                      // A-operand: weight rows [n][k]
            #pragma unroll
            for (int ks = 0; ks < 4; ++ks)
                wf[ks] = *(const bf16x8*)&Bs[nw + nt * 16 + n16][ks * 32 + quad * 8];
            #pragma unroll
            for (int ks = 0; ks < 4; ++ks)
                #pragma unroll
                for (int mt = 0; mt < 2; ++mt)
                    acc[mt][nt] = __builtin_amdgcn_mfma_f32_16x16x32_bf16(wf[ks], pf[mt][ks], acc[mt][nt], 0, 0, 0);
        }
        __syncthreads();                       // all waves done reading Bs

        u128 breg[3];
        if (nc < 3) {                          // issue next-chunk B loads NOW
            #pragma unroll
            for (int it = 0; it < 3; ++it) {
                int idx = it * 512 + t;
                int n = idx >> 4, c8 = (idx & 15) * 8;
                breg[it] = *(const u128*)(Bt + (size_t)(n0 + 96 + n) * CC + c8);
            }
        }

        // epilogue for this chunk (covers the B-load latency)
        #pragma unroll
        for (int nt = 0; nt < 3; ++nt) {
            int nbase = n0 + nw + nt * 16 + quad * 4;
            float4 b4 = *(const float4*)(bias + nbase);
            float sc = (nbase < CC) ? QSC : 1.0f;  // group of 4 never straddles 128
            #pragma unroll
            for (int mt = 0; mt < 2; ++mt) {
                int m = m0 + mw + mt * 16 + n16;
                __hip_bfloat162 h01 = __float22bfloat162_rn(float2{(acc[mt][nt][0] + b4.x) * sc, (acc[mt][nt][1] + b4.y) * sc});
                __hip_bfloat162 h23 = __float22bfloat162_rn(float2{(acc[mt][nt][2] + b4.z) * sc, (acc[mt][nt][3] + b4.w) * sc});
                uint2 pk;
                pk.x = *(unsigned int*)&h01;
                pk.y = *(unsigned int*)&h23;
                *(uint2*)&out[(size_t)m * 384 + nbase] = pk;
            }
        }

        if (nc < 3) {
            #pragma unroll
            for (int it = 0; it < 3; ++it) {
                int idx = it * 512 + t;
                int n = idx >> 4, c8 = (idx & 15) * 8;
                *(u128*)&Bs[n][c8] = breg[it];
            }
            __syncthreads();                   // Bs ready for next chunk
        }
    }
}

// ---------------------------------------------------------------------------
// K2: MFMA attention, S^T formulation, 512 threads (8 waves). UNCHANGED (R5).
//   Coalesced bias2 loads ride the MFMA C-operand; V staged k-permuted so
//   exp2'd P packs straight into the PV B-frag; LDS 37 KB, 62% occupancy.
// ---------------------------------------------------------------------------
__global__ __launch_bounds__(512, 8) void attn_mfma_kernel(
    const __hip_bfloat16* __restrict__ qkv,   // [65536,384]
    const float* __restrict__ bias2,          // [256,256] permuted, *log2e
    __hip_bfloat16* __restrict__ attn_out)    // [65536,128]
{
    __shared__ __align__(16) __hip_bfloat16 Ks[NN][40];      // 20.0 KB
    __shared__ __align__(16) __hip_bfloat16 VTs[DD][264];    // 16.5 KB

    const int bi = blockIdx.x;
    const int i = bi >> 2, h = bi & 3;
    const int t = threadIdx.x;

    {   // stage K rows + permuted V^T with ALL 512 threads
        const int r = t >> 1, half = t & 1;
        const __hip_bfloat16* base = qkv + (size_t)(i * NN + r) * 384 + h * DD;
        const u128* ksrc = (const u128*)(base + CC) + half * 2;
        u128* kdst = (u128*)&Ks[r][0] + half * 2;
        kdst[0] = ksrc[0];
        kdst[1] = ksrc[1];
        const u128* vsrc = (const u128*)(base + 2 * CC) + half * 2;
        u128 vr[2];
        vr[0] = vsrc[0];
        vr[1] = vsrc[1];
        const __hip_bfloat16* vh = (const __hip_bfloat16*)vr;
        // k-bit swizzle: k = [b4|q1 q0|r1 r0] -> pos = [q1 q0|b4|r1 r0]
        const int pr = (r & ~0x1F) | ((r & 0xC) << 1) | ((r & 0x10) >> 2) | (r & 0x3);
        #pragma unroll
        for (int dd = 0; dd < 16; ++dd) VTs[half * 16 + dd][pr] = vh[dd];
    }
    __syncthreads();

    const int w = t >> 6, lane = t & 63;
    const int n16 = lane & 15, quad = lane >> 4;

    #pragma unroll
    for (int jt = 0; jt < 2; ++jt) {
        const int j0 = w * 32 + jt * 16;
        const int j = j0 + n16;                // this lane's softmax column
        const int jblk = w * 2 + jt;           // j0 >> 4

        // Q B-frag for row j
        bf16x8 qa = *(const bf16x8*)(qkv + (size_t)(i * NN + j) * 384 + h * DD + quad * 8);
        const float4* bb = (const float4*)bias2;

        f32x4 sm = {0.f, 0.f, 0.f, 0.f};
        f32x4 o0 = {0.f, 0.f, 0.f, 0.f}, o1 = {0.f, 0.f, 0.f, 0.f};

        #pragma unroll 2
        for (int c = 0; c < 8; ++c) {
            // bias rides the MFMA C-operand; loads are lane-contiguous
            float4 b0 = bb[((c * 2 + 0) * 16 + jblk) * 64 + lane];
            float4 b1 = bb[((c * 2 + 1) * 16 + jblk) * 64 + lane];
            bf16x8 kb0 = *(const bf16x8*)&Ks[c * 32 + n16][quad * 8];
            bf16x8 kb1 = *(const bf16x8*)&Ks[c * 32 + 16 + n16][quad * 8];
            f32x4 s0 = __builtin_amdgcn_mfma_f32_16x16x32_bf16(
                kb0, qa, (f32x4){b0.x, b0.y, b0.z, b0.w}, 0, 0, 0);
            f32x4 s1 = __builtin_amdgcn_mfma_f32_16x16x32_bf16(
                kb1, qa, (f32x4){b1.x, b1.y, b1.z, b1.w}, 0, 0, 0);

            float p0 = __builtin_amdgcn_exp2f(s0[0]);
            float p1 = __builtin_amdgcn_exp2f(s0[1]);
            float p2 = __builtin_amdgcn_exp2f(s0[2]);
            float p3 = __builtin_amdgcn_exp2f(s0[3]);
            float p4 = __builtin_amdgcn_exp2f(s1[0]);
            float p5 = __builtin_amdgcn_exp2f(s1[1]);
            float p6 = __builtin_amdgcn_exp2f(s1[2]);
            float p7 = __builtin_amdgcn_exp2f(s1[3]);
            sm[0] += p0 + p4;
            sm[1] += p1 + p5;
            sm[2] += p2 + p6;
            sm[3] += p3 + p7;

            // pack straight into the PV B-frag (V was staged permuted)
            __hip_bfloat162 q01 = __float22bfloat162_rn(float2{p0, p1});
            __hip_bfloat162 q23 = __float22bfloat162_rn(float2{p2, p3});
            __hip_bfloat162 q45 = __float22bfloat162_rn(float2{p4, p5});
            __hip_bfloat162 q67 = __float22bfloat162_rn(float2{p6, p7});
            u128 pk;
            pk.x = *(unsigned int*)&q01;
            pk.y = *(unsigned int*)&q23;
            pk.z = *(unsigned int*)&q45;
            pk.w = *(unsigned int*)&q67;
            bf16x8 pa = *(bf16x8*)&pk;

            bf16x8 vb0 = *(const bf16x8*)&VTs[n16][c * 32 + quad * 8];
            bf16x8 vb1 = *(const bf16x8*)&VTs[16 + n16][c * 32 + quad * 8];
            o0 = __builtin_amdgcn_mfma_f32_16x16x32_bf16(vb0, pa, o0, 0, 0, 0);
            o1 = __builtin_amdgcn_mfma_f32_16x16x32_bf16(vb1, pa, o1, 0, 0, 0);
        }

        float sum = (sm[0] + sm[1]) + (sm[2] + sm[3]);
        sum += __shfl_xor(sum, 16);
        sum += __shfl_xor(sum, 32);
        float inv = 1.0f / sum;

        // store: column j (same lane as softmax -> own inv), packed d
        __hip_bfloat16* obase = attn_out + (size_t)(i * NN + j) * CC + h * DD + quad * 4;
        {
            __hip_bfloat162 h01 = __float22bfloat162_rn(float2{o0[0] * inv, o0[1] * inv});
            __hip_bfloat162 h23 = __float22bfloat162_rn(float2{o0[2] * inv, o0[3] * inv});
            uint2 pk;
            pk.x = *(unsigned int*)&h01;
            pk.y = *(unsigned int*)&h23;
            *(uint2*)(obase) = pk;
        }
        {
            __hip_bfloat162 h01 = __float22bfloat162_rn(float2{o1[0] * inv, o1[1] * inv});
            __hip_bfloat162 h23 = __float22bfloat162_rn(float2{o1[2] * inv, o1[3] * inv});
            uint2 pk;
            pk.x = *(unsigned int*)&h01;
            pk.y = *(unsigned int*)&h23;
            *(uint2*)(obase + 16) = pk;
        }
    }
}

// ---------------------------------------------------------------------------
// K3: out = attn_out @ Wout + bout  (MFMA, operand-swapped -> float4 stores)
// Staging batch-loaded: all 8 u128 loads in flight before any LDS write.
// ---------------------------------------------------------------------------
__global__ __launch_bounds__(512, 4) void out_mfma_kernel(
    const __hip_bfloat16* __restrict__ A,     // [65536,128] bf16
    const __hip_bfloat16* __restrict__ Bt,    // [128,128] bf16 (transposed W)
    const float* __restrict__ bias,           // [128]
    float* __restrict__ out)                  // [65536,128]
{
    __shared__ __align__(16) __hip_bfloat16 As[128][136];
    __shared__ __align__(16) __hip_bfloat16 Bs[128][136];
    const int t = threadIdx.x;
    const int m0 = blockIdx.x * 128;

    u128 ra[4], rb[4];
    #pragma unroll
    for (int it = 0; it < 4; ++it) {
        int idx = it * 512 + t;
        int r = idx >> 4, c8 = (idx & 15) * 8;
        ra[it] = *(const u128*)(A + (size_t)(m0 + r) * CC + c8);
    }
    #pragma unroll
    for (int it = 0; it < 4; ++it) {
        int idx = it * 512 + t;
        int n = idx >> 4, c8 = (idx & 15) * 8;
        rb[it] = *(const u128*)(Bt + (size_t)n * CC + c8);
    }
    #pragma unroll
    for (int it = 0; it < 4; ++it) {
        int idx = it * 512 + t;
        int r = idx >> 4, c8 = (idx & 15) * 8;
        *(u128*)&As[r][c8] = ra[it];
    }
    #pragma unroll
    for (int it = 0; it < 4; ++it) {
        int idx = it * 512 + t;
        int n = idx >> 4, c8 = (idx & 15) * 8;
        *(u128*)&Bs[n][c8] = rb[it];
    }
    __syncthreads();

    const int w = t >> 6, lane = t & 63;
    const int n16 = lane & 15, quad = lane >> 4;
    const int mw = (w & 3) * 32, nw = (w >> 2) * 64;

    bf16x8 pf[2][4];
    #pragma unroll
    for (int mt = 0; mt < 2; ++mt)
        #pragma unroll
        for (int ks = 0; ks < 4; ++ks)
            pf[mt][ks] = *(const bf16x8*)&As[mw + mt * 16 + n16][ks * 32 + quad * 8];

    f32x4 acc[2][4];
    #pragma unroll
    for (int mt = 0; mt < 2; ++mt)
        #pragma unroll
        for (int nt = 0; nt < 4; ++nt) acc[mt][nt] = (f32x4){0.f, 0.f, 0.f, 0.f};

    #pragma unroll
    for (int nt = 0; nt < 4; ++nt) {
        bf16x8 wf[4];
        #pragma unroll
        for (int ks = 0; ks < 4; ++ks)
            wf[ks] = *(const bf16x8*)&Bs[nw + nt * 16 + n16][ks * 32 + quad * 8];
        #pragma unroll
        for (int ks = 0; ks < 4; ++ks)
            #pragma unroll
            for (int mt = 0; mt < 2; ++mt)
                acc[mt][nt] = __builtin_amdgcn_mfma_f32_16x16x32_bf16(wf[ks], pf[mt][ks], acc[mt][nt], 0, 0, 0);
    }

    #pragma unroll
    for (int nt = 0; nt < 4; ++nt) {
        int nbase = nw + nt * 16 + quad * 4;
        float4 b4 = *(const float4*)(bias + nbase);
        #pragma unroll
        for (int mt = 0; mt < 2; ++mt) {
            int m = m0 + mw + mt * 16 + n16;
            float4 ov;
            ov.x = acc[mt][nt][0] + b4.x;
            ov.y = acc[mt][nt][1] + b4.y;
            ov.z = acc[mt][nt][2] + b4.z;
            ov.w = acc[mt][nt][3] + b4.w;
            *(float4*)&out[(size_t)m * CC + nbase] = ov;
        }
    }
}

// ---------------------------------------------------------------------------
extern "C" void kernel_launch(void* const* d_in, const int* in_sizes, int n_in,
                              void* d_out, int out_size, void* d_ws, size_t ws_size,
                              hipStream_t stream) {
    const float* pair_rep = (const float*)d_in[0];
    const float* dm       = (const float*)d_in[1];
    const float* Wqkv     = (const float*)d_in[2];
    const float* bqkv     = (const float*)d_in[3];
    const float* Wout     = (const float*)d_in[4];
    const float* bout     = (const float*)d_in[5];
    const float* dscale   = (const float*)d_in[6];
    const int*   mask     = (const int*)d_in[7];
    float* out = (float*)d_out;

    // ws: bias2[256KB] | Wt_qkv[96KB] | Wt_out[32KB] | qkv[48MB] | attn[16MB]
    char* p = (char*)d_ws;
    float* bias2 = (float*)p;                 p += (size_t)NN * NN * 4;
    __hip_bfloat16* Wt_qkv = (__hip_bfloat16*)p;  p += (size_t)384 * CC * 2;
    __hip_bfloat16* Wt_out = (__hip_bfloat16*)p;  p += (size_t)CC * CC * 2;
    __hip_bfloat16* qkv  = (__hip_bfloat16*)p;    p += (size_t)65536 * 384 * 2;
    __hip_bfloat16* attn = (__hip_bfloat16*)p;

    prep_kernel<<<dim3(512), dim3(256), 0, stream>>>(dm, mask, dscale, Wqkv, Wout, bias2, Wt_qkv, Wt_out);
    qkv_mfma_kernel<<<dim3(512), dim3(512), 0, stream>>>(pair_rep, Wt_qkv, bqkv, qkv);
    attn_mfma_kernel<<<dim3(1024), dim3(512), 0, stream>>>(qkv, bias2, attn);
    out_mfma_kernel<<<dim3(512), dim3(512), 0, stream>>>(attn, Wt_out, bout, out);
}